// Round 6
// baseline (211.411 us; speedup 1.0000x reference)
//
#include <hip/hip_runtime.h>
#include <hip/hip_bf16.h>
#include <cstdint>
#include <cstddef>

typedef __bf16 bf16_t;
typedef __bf16 bf16x8 __attribute__((ext_vector_type(8)));
typedef __bf16 bf16x4 __attribute__((ext_vector_type(4)));
typedef float f32x4 __attribute__((ext_vector_type(4)));

#define DM 1024
#define NHEAD 16
#define DHEAD 64

// Q scale folded into projection: 1/sqrt(64) * log2(e)
#define QSCALE 0.18033688011112042f
// fixed exp2 shift (cancels exactly in O/l)
#define PSHIFT 4.0f
// padded LDS row stride for attention tiles
#define RS 72

// counted vmcnt: lets N loads stay in flight across a raw barrier (T4)
#define WAITVM(N) asm volatile("s_waitcnt vmcnt(" #N ")" ::: "memory")
#define LGKM0()   asm volatile("s_waitcnt lgkmcnt(0)" ::: "memory")
#define BAR()     do { asm volatile("" ::: "memory"); __builtin_amdgcn_s_barrier(); \
                       asm volatile("" ::: "memory"); } while (0)
// pack 2 f32 -> 2 bf16 in one u32 (no builtin on gfx950; RNE)
#define CVTPK(d, a, b) asm("v_cvt_pk_bf16_f32 %0, %1, %2" : "=v"(d) : "v"(a), "v"(b))

__device__ __forceinline__ void gload_lds16(const void* g, void* l) {
    __builtin_amdgcn_global_load_lds(
        (const __attribute__((address_space(1))) void*)g,
        (__attribute__((address_space(3))) void*)l,
        16, 0, 0);
}

// ---------------- prep: W transpose only (X-cast fused into gemm_qkv) -------
// 1024 blocks: matrix id>>8, 64x64 tile.
__global__ void prep(
    const float* __restrict__ w0, const float* __restrict__ w1,
    const float* __restrict__ w2, const float* __restrict__ w3,
    bf16_t* __restrict__ t0, bf16_t* __restrict__ t1,
    bf16_t* __restrict__ t2, bf16_t* __restrict__ t3)
{
    __shared__ float tile[64][65];
    int id = blockIdx.x;
    int zi = id >> 8;
    int blk = id & 255;
    const float* w = zi == 0 ? w0 : zi == 1 ? w1 : zi == 2 ? w2 : w3;
    bf16_t* wt     = zi == 0 ? t0 : zi == 1 ? t1 : zi == 2 ? t2 : t3;
    int bx = (blk & 15) * 64;    // n base
    int by = (blk >> 4) * 64;    // k base
    int tx = threadIdx.x & 63, ty = threadIdx.x >> 6;   // 64 x 4
    for (int j = 0; j < 64; j += 4)
        tile[ty + j][tx] = w[(size_t)(by + ty + j) * DM + bx + tx];
    __syncthreads();
    int nl = threadIdx.x >> 3;           // 0..31
    int kl = (threadIdx.x & 7) * 8;      // 0..56
    for (int j = 0; j < 64; j += 32) {
        int n = nl + j;
        union { bf16_t b[8]; uint4 u; } o;
        for (int i = 0; i < 8; i++)
            o.b[i] = (bf16_t)tile[kl + i][n];
        *(uint4*)&wt[(size_t)(bx + n) * DM + by + kl] = o.u;
    }
}

// ---- GEMM core: 128x128, BK=32, 3-slot depth-2, one f32 operand in-kernel --
// One side (X) is f32 in HBM: reg-staged (4 dwordx4) -> cvt_pk -> 2
// ds_write_b128 into the SAME bf16 LDS layout as the gload_lds side.
// Ledger (6 issues/step: 2 gload_lds + 4 f32 loads, FIFO): single WAITVM(6)
// per step retires ALL of step t+1's issues (the 6 newest are this step's,
// robust to intra-step reordering), leaving t+2's 6 in flight across the
// raw barrier. cvt+ds_write of tile t+1 lands after the wait; lgkmcnt(0)
// publishes it at the barrier. Slots: write slot (t+1)%3 freed at barrier
// end of step t-2; issue slot (t+2)%3 freed at end of step t-1.
// Chunk-XOR swizzle both-sides as in round 5 (source-swizzled, read ^ch).
// MODE 1: bf16 out [bh][s][d], v=(acc+bias[C])*scale  (AF32: A = X f32)
// MODE 2: bf16 out Vt [bh][d][s], v=acc+bias[R]       (!AF32: B = X f32)
template <int MODE, bool AF32>
__device__ __forceinline__ void gemm_body(
    const void* __restrict__ Aop, const void* __restrict__ Bop,
    const float* __restrict__ bias, float scale,
    bf16_t* __restrict__ Cb,
    int r0, int c0, bf16_t* AsP, bf16_t* BsP)
{
    const int K = 1024;
    int tid  = threadIdx.x;
    int wave = tid >> 6;
    int lane = tid & 63;
    int quad = lane >> 4;
    int ln   = lane & 15;
    int wr   = wave >> 1;
    int wc   = wave & 1;

    f32x4 acc[4][4];
    for (int rb = 0; rb < 4; rb++)
        for (int cb = 0; cb < 4; cb++)
            acc[rb][cb] = (f32x4){0.f, 0.f, 0.f, 0.f};

    int sr  = tid >> 2;
    int sk8 = ((tid & 3) ^ ((tid >> 3) & 3)) * 8;   // swizzled source chunk

    const float*  fF;   // f32 side (reg-staged)
    const bf16_t* gG0;  // bf16 side (gload_lds)
    char* lF; char* lG;
    if (AF32) {
        fF  = (const float*)Aop  + (size_t)(r0 + sr) * K + sk8;
        gG0 = (const bf16_t*)Bop + (size_t)(c0 + sr) * K + sk8;
        lF  = (char*)AsP + tid * 16;     // explicit ds_write dest (linear)
        lG  = (char*)BsP + wave * 1024;  // gload_lds wave base
    } else {
        fF  = (const float*)Bop  + (size_t)(c0 + sr) * K + sk8;
        gG0 = (const bf16_t*)Aop + (size_t)(r0 + sr) * K + sk8;
        lF  = (char*)BsP + tid * 16;
        lG  = (char*)AsP + wave * 1024;
    }
    const float*  fF1 = fF  + (size_t)64 * K;
    const bf16_t* gG1 = gG0 + (size_t)64 * K;

    int ch = (quad ^ ((ln >> 1) & 3)) * 8;   // swizzled read chunk

    f32x4 f0_0, f0_1, f0_2, f0_3;   // two in-flight f32 tile reg-sets
    f32x4 f1_0, f1_1, f1_2, f1_3;

#define F_ISSUE(S, kk) do { \
    f##S##_0 = *(const f32x4*)(fF  + (kk)); \
    f##S##_1 = *(const f32x4*)(fF  + (kk) + 4); \
    f##S##_2 = *(const f32x4*)(fF1 + (kk)); \
    f##S##_3 = *(const f32x4*)(fF1 + (kk) + 4); \
} while (0)

#define F_WRITE(S, SLOT) do { \
    uint4 w0, w1; \
    CVTPK(w0.x, f##S##_0.x, f##S##_0.y); CVTPK(w0.y, f##S##_0.z, f##S##_0.w); \
    CVTPK(w0.z, f##S##_1.x, f##S##_1.y); CVTPK(w0.w, f##S##_1.z, f##S##_1.w); \
    CVTPK(w1.x, f##S##_2.x, f##S##_2.y); CVTPK(w1.y, f##S##_2.z, f##S##_2.w); \
    CVTPK(w1.z, f##S##_3.x, f##S##_3.y); CVTPK(w1.w, f##S##_3.z, f##S##_3.w); \
    *(uint4*)(lF + (SLOT) * 8192)        = w0; \
    *(uint4*)(lF + (SLOT) * 8192 + 4096) = w1; \
} while (0)

    auto G_ISSUE = [&](int kk, int slot) {
        gload_lds16(gG0 + kk, lG + slot * 8192);
        gload_lds16(gG1 + kk, lG + slot * 8192 + 4096);
    };
    auto COMPUTE = [&](int slot) {
        const bf16_t* Ab = AsP + slot * 4096;   // 4096 elems = 8 KB slot
        const bf16_t* Bb = BsP + slot * 4096;
        bf16x8 af[4], bfv[4];
        #pragma unroll
        for (int rb = 0; rb < 4; rb++)
            af[rb] = *(const bf16x8*)&Ab[(wr * 64 + rb * 16 + ln) * 32 + ch];
        #pragma unroll
        for (int cb = 0; cb < 4; cb++)
            bfv[cb] = *(const bf16x8*)&Bb[(wc * 64 + cb * 16 + ln) * 32 + ch];
        __builtin_amdgcn_s_setprio(1);
        #pragma unroll
        for (int rb = 0; rb < 4; rb++)
            #pragma unroll
            for (int cb = 0; cb < 4; cb++)
                acc[rb][cb] = __builtin_amdgcn_mfma_f32_16x16x32_bf16(af[rb], bfv[cb], acc[rb][cb], 0, 0, 0);
        __builtin_amdgcn_s_setprio(0);
    };

    // prologue: tiles 0,1 issued; WAITVM(6) retires tile0's 6 (G0,F0); write A0.
    G_ISSUE(0, 0);  F_ISSUE(0, 0);
    G_ISSUE(32, 1); F_ISSUE(1, 32);
    WAITVM(6);
    F_WRITE(0, 0);
    LGKM0(); BAR();

    // steps t=0..29: slot t%3, issue slot (t+2)%3, write slot (t+1)%3,
    // issue reg-set t&1, write reg-set (t+1)&1. Period 6, 5 iterations.
    int kk = 64;
    for (int t6 = 0; t6 < 5; ++t6) {
        G_ISSUE(kk, 2); F_ISSUE(0, kk); COMPUTE(0);
        WAITVM(6); F_WRITE(1, 1); LGKM0(); BAR(); kk += 32;

        G_ISSUE(kk, 0); F_ISSUE(1, kk); COMPUTE(1);
        WAITVM(6); F_WRITE(0, 2); LGKM0(); BAR(); kk += 32;

        G_ISSUE(kk, 1); F_ISSUE(0, kk); COMPUTE(2);
        WAITVM(6); F_WRITE(1, 0); LGKM0(); BAR(); kk += 32;

        G_ISSUE(kk, 2); F_ISSUE(1, kk); COMPUTE(0);
        WAITVM(6); F_WRITE(0, 1); LGKM0(); BAR(); kk += 32;

        G_ISSUE(kk, 0); F_ISSUE(0, kk); COMPUTE(1);
        WAITVM(6); F_WRITE(1, 2); LGKM0(); BAR(); kk += 32;

        G_ISSUE(kk, 1); F_ISSUE(1, kk); COMPUTE(2);
        WAITVM(6); F_WRITE(0, 0); LGKM0(); BAR(); kk += 32;
    }
    // epilogue: t=30 (slot 0), then t=31 (slot 1; tile31 loaded at t=29 -> set1)
    COMPUTE(0); WAITVM(0); F_WRITE(1, 1); LGKM0(); BAR();
    COMPUTE(1);

#undef F_ISSUE
#undef F_WRITE

    for (int rb = 0; rb < 4; rb++) {
        for (int cb = 0; cb < 4; cb++) {
            int C = c0 + wc * 64 + cb * 16 + ln;
            for (int r = 0; r < 4; r++) {
                int R = r0 + wr * 64 + rb * 16 + quad * 4 + r;
                float v = acc[rb][cb][r];
                if (MODE == 1) {
                    int b = R >> 10, s = R & 1023;
                    int h = C >> 6,  d = C & 63;
                    Cb[(((size_t)b * NHEAD + h) * 1024 + s) * DHEAD + d] =
                        (bf16_t)((v + bias[C]) * scale);
                } else {
                    Cb[((size_t)(C >> 10) * 1024 + R) * 1024 + (C & 1023)] =
                        (bf16_t)(v + bias[R]);
                }
            }
        }
    }
}

// grid (32, 8, 3): x = M-tile (XCD locality: id%8 = x%8), y = N-tile.
__global__ __launch_bounds__(256, 3) void gemm_qkv(
    const float* __restrict__ q_in, const float* __restrict__ k_in, const float* __restrict__ v_in,
    const bf16_t* __restrict__ Wtq, const bf16_t* __restrict__ Wtk, const bf16_t* __restrict__ Wtv,
    const float* __restrict__ bq, const float* __restrict__ bk, const float* __restrict__ bv,
    bf16_t* __restrict__ Qd, bf16_t* __restrict__ Kd, bf16_t* __restrict__ Vt)
{
    __shared__ __align__(16) bf16_t As[3 * 128 * 32];   // 24 KB
    __shared__ __align__(16) bf16_t Bs[3 * 128 * 32];   // 24 KB
    int z = blockIdx.z;
    if (z == 0) {
        gemm_body<1, true>(q_in, Wtq, bq, QSCALE, Qd,
                           blockIdx.x * 128, blockIdx.y * 128, As, Bs);
    } else if (z == 1) {
        gemm_body<1, true>(k_in, Wtk, bk, 1.0f, Kd,
                           blockIdx.x * 128, blockIdx.y * 128, As, Bs);
    } else {
        // Vt = (Xv Wv)^T : A = Wtv (bf16, 8 channel tiles = y), B = v_in (f32, 32 token tiles = x)
        gemm_body<2, false>(Wtv, v_in, bv, 1.0f, Vt,
                            blockIdx.y * 128, blockIdx.x * 128, As, Bs);
    }
}

// ---------------- output projection: 64x128, 3-buffer depth-2 (round-5) ----
__global__ __launch_bounds__(256, 2) void gemm_out(
    const bf16_t* __restrict__ At, const bf16_t* __restrict__ Wto,
    const float* __restrict__ bo, float* __restrict__ out)
{
    const int K = 1024;
    __shared__ __align__(16) bf16_t As[3 * 64 * 32];    // 12 KB
    __shared__ __align__(16) bf16_t Bs[3 * 128 * 32];   // 24 KB

    int tid  = threadIdx.x;
    int wave = tid >> 6;
    int lane = tid & 63;
    int quad = lane >> 4;
    int ln   = lane & 15;

    int r0 = blockIdx.x * 64;
    int c0 = blockIdx.y * 128;

    f32x4 acc[4][2];
    for (int rb = 0; rb < 4; rb++)
        for (int cb = 0; cb < 2; cb++)
            acc[rb][cb] = (f32x4){0.f, 0.f, 0.f, 0.f};

    int sr = tid >> 2;
    int sk = (((tid & 3) ^ ((tid >> 3) & 3))) * 8;

    const bf16_t* gA0 = At  + (size_t)(r0 + sr) * K + sk;
    const bf16_t* gB0 = Wto + (size_t)(c0 + sr) * K + sk;
    const bf16_t* gB1 = gB0 + (size_t)64 * K;
    char* lA = (char*)As + wave * 1024;   // slot stride 4096 B
    char* lB = (char*)Bs + wave * 1024;   // slot stride 8192 B

    int ch = (quad ^ ((ln >> 1) & 3)) * 8;

    auto STAGE = [&](int s, int slot) {
        int k = s * 32;
        gload_lds16(gA0 + k, lA + slot * 4096);
        gload_lds16(gB0 + k, lB + slot * 8192);
        gload_lds16(gB1 + k, lB + slot * 8192 + 4096);
    };
    auto COMPUTE = [&](int slot) {
        const bf16_t* Ab = As + slot * 2048;
        const bf16_t* Bb = Bs + slot * 4096;
        bf16x8 af[4], bfv[2];
        #pragma unroll
        for (int rb = 0; rb < 4; rb++)
            af[rb] = *(const bf16x8*)&Ab[(rb * 16 + ln) * 32 + ch];
        #pragma unroll
        for (int cb = 0; cb < 2; cb++)
            bfv[cb] = *(const bf16x8*)&Bb[(wave * 32 + cb * 16 + ln) * 32 + ch];
        __builtin_amdgcn_s_setprio(1);
        #pragma unroll
        for (int rb = 0; rb < 4; rb++)
            #pragma unroll
            for (int cb = 0; cb < 2; cb++)
                acc[rb][cb] = __builtin_amdgcn_mfma_f32_16x16x32_bf16(af[rb], bfv[cb], acc[rb][cb], 0, 0, 0);
        __builtin_amdgcn_s_setprio(0);
    };

    STAGE(0, 0); STAGE(1, 1);
    WAITVM(3);
    BAR();

    for (int tt = 0; tt < 30; tt += 3) {
        STAGE(tt + 2, 2); COMPUTE(0); WAITVM(3); BAR();
        STAGE(tt + 3, 0); COMPUTE(1); WAITVM(3); BAR();
        STAGE(tt + 4, 1); COMPUTE(2); WAITVM(3); BAR();
    }
    COMPUTE(0); WAITVM(0); BAR();
    COMPUTE(1);

    for (int rb = 0; rb < 4; rb++) {
        for (int cb = 0; cb < 2; cb++) {
            int C = c0 + wave * 32 + cb * 16 + ln;
            float bn = bo[C];
            for (int r = 0; r < 4; r++) {
                int R = r0 + rb * 16 + quad * 4 + r;
                out[(size_t)R * DM + C] = acc[rb][cb][r] + bn;
            }
        }
    }
}

// ---------------- flash attention: K/V LDS dbuf, 1 barrier/kt (round-5) -----
__global__ __launch_bounds__(256) void attn7(
    const bf16_t* __restrict__ Q,
    const bf16_t* __restrict__ K,
    const bf16_t* __restrict__ Vt,
    bf16_t* __restrict__ O)
{
    __shared__ __align__(16) bf16_t Ks[2][64 * RS];
    __shared__ __align__(16) bf16_t Vs[2][64 * RS];
    __shared__ __align__(16) bf16_t Ps[4][32 * RS];

    int tid  = threadIdx.x;
    int wave = tid >> 6;
    int lane = tid & 63;
    int quad = lane >> 4;
    int ln   = lane & 15;

    int bh = blockIdx.x;
    int q0w = blockIdx.y * 128 + wave * 32;

    const bf16_t* Qb = Q  + (size_t)bh * 65536;
    const bf16_t* Kb = K  + (size_t)bh * 65536;
    const bf16_t* Vb = Vt + (size_t)bh * 65536;

    int srow = tid >> 3;
    int scol = (tid & 7) * 8;
    const bf16_t* gK0 = Kb + (size_t)srow * 64 + scol;
    const bf16_t* gK1 = gK0 + 32 * 64;
    const bf16_t* gV0 = Vb + (size_t)srow * 1024 + scol;
    const bf16_t* gV1 = gV0 + 32 * 1024;

    bf16x8 aq0[2], aq1[2];
    for (int h = 0; h < 2; h++) {
        aq0[h] = *(const bf16x8*)&Qb[(size_t)(q0w + h * 16 + ln) * 64 + quad * 8];
        aq1[h] = *(const bf16x8*)&Qb[(size_t)(q0w + h * 16 + ln) * 64 + 32 + quad * 8];
    }

    uint4 rK0 = *(const uint4*)gK0;
    uint4 rK1 = *(const uint4*)gK1;
    uint4 rV0 = *(const uint4*)gV0;
    uint4 rV1 = *(const uint4*)gV1;
    *(uint4*)&Ks[0][srow * RS + scol]        = rK0;
    *(uint4*)&Ks[0][(32 + srow) * RS + scol] = rK1;
    *(uint4*)&Vs[0][srow * RS + scol]        = rV0;
    *(uint4*)&Vs[0][(32 + srow) * RS + scol] = rV1;
    gK0 += 4096; gK1 += 4096; gV0 += 64; gV1 += 64;
    rK0 = *(const uint4*)gK0;
    rK1 = *(const uint4*)gK1;
    rV0 = *(const uint4*)gV0;
    rV1 = *(const uint4*)gV1;

    float l_lane[2] = {0.f, 0.f};
    f32x4 o_acc[2][4];
    for (int h = 0; h < 2; h++)
        for (int cb = 0; cb < 4; cb++)
            o_acc[h][cb] = (f32x4){0.f, 0.f, 0.f, 0.f};

    bf16_t* Pw = Ps[wave];

    LGKM0();
    BAR();

    for (int kt = 0; kt < 16; kt++) {
        const bf16_t* Kc = Ks[kt & 1];
        const bf16_t* Vc = Vs[kt & 1];
        bf16_t* Kn = Ks[(kt + 1) & 1];
        bf16_t* Vn = Vs[(kt + 1) & 1];

        if (kt < 15) {
            *(uint4*)&Kn[srow * RS + scol]        = rK0;
            *(uint4*)&Kn[(32 + srow) * RS + scol] = rK1;
            *(uint4*)&Vn[srow * RS + scol]        = rV0;
            *(uint4*)&Vn[(32 + srow) * RS + scol] = rV1;
        }
        if (kt < 14) {
            gK0 += 4096; gK1 += 4096; gV0 += 64; gV1 += 64;
            rK0 = *(const uint4*)gK0;
            rK1 = *(const uint4*)gK1;
            rV0 = *(const uint4*)gV0;
            rV1 = *(const uint4*)gV1;
        }

        // ---- S^T = K Q^T (two 16-row q-halves share K fragments) ----
        f32x4 sc[4][2];
        for (int kb = 0; kb < 4; kb++) {
            bf16x8 kf0 = *(const bf16x8*)&Kc[(kb * 16 + ln) * RS + quad * 8];
            bf16x8 kf1 = *(const bf16x8*)&Kc[(kb * 16 + ln) * RS + 32 + quad * 8];
            for (int h = 0; h < 2; h++) {
                f32x4 a = (f32x4){0.f, 0.f, 0.f, 0.f};
                a = __builtin_amdgcn_mfma_f32_16x16x32_bf16(kf0, aq0[h], a, 0, 0, 0);
                a = __builtin_amdgcn_mfma_f32_16x16x32_bf16(kf1, aq1[h], a, 0, 0, 0);
                sc[kb][h] = a;
            }
        }

        // ---- P = exp2(sc - PSHIFT) ----
        for (int kb = 0; kb < 4; kb++) {
            for (int h = 0; h < 2; h++) {
                float p0 = __builtin_amdgcn_exp2f(sc[kb][h][0] - PSHIFT);
                float p1 = __builtin_amdgcn_exp2f(sc[kb][h][1] - PSHIFT);
                float p2 = __builtin_amdgcn_exp2f(sc[kb][h][2] - PSHIFT);
                float p3 = __builtin_amdgcn_exp2f(sc[kb][h][3] - PSHIFT);
                l_lane[h] += (p0 + p1) + (p2 + p3);
                bf16x4 pk = (bf16x4){(bf16_t)p0, (bf16_t)p1, (bf16_t)p2, (bf16_t)p3};
                *(bf16x4*)&Pw[(h * 16 + ln) * RS + kb * 16 + quad * 4] = pk;
            }
        }

        // ---- O += P V (V fragments shared across q-halves) ----
        for (int kc = 0; kc < 2; kc++) {
            bf16x8 ap0 = *(const bf16x8*)&Pw[ln * RS + kc * 32 + quad * 8];
            bf16x8 ap1 = *(const bf16x8*)&Pw[(16 + ln) * RS + kc * 32 + quad * 8];
            for (int cb = 0; cb < 4; cb++) {
                bf16x8 vf = *(const bf16x8*)&Vc[(cb * 16 + ln) * RS + kc * 32 + quad * 8];
                o_acc[0][cb] = __builtin_amdgcn_mfma_f32_16x16x32_bf16(ap0, vf, o_acc[0][cb], 0, 0, 0);
                o_acc[1][cb] = __builtin_amdgcn_mfma_f32_16x16x32_bf16(ap1, vf, o_acc[1][cb], 0, 0, 0);
            }
        }

        if (kt < 15) {
            LGKM0();   // publish kt+1 stores
            BAR();     // vmcnt prefetch stays in flight
        }
    }

    int b = bh >> 4, hd = bh & 15;
    for (int h = 0; h < 2; h++) {
        float l = l_lane[h];
        l += __shfl_xor(l, 16);
        l += __shfl_xor(l, 32);
        float invq[4];
        for (int r = 0; r < 4; r++)
            invq[r] = 1.f / __shfl(l, quad * 4 + r);
        for (int cb = 0; cb < 4; cb++) {
            for (int r = 0; r < 4; r++) {
                int q = q0w + h * 16 + quad * 4 + r;
                int d = cb * 16 + ln;
                O[((size_t)b * 1024 + q) * DM + hd * 64 + d] = (bf16_t)(o_acc[h][cb][r] * invq[r]);
            }
        }
    }
}

extern "C" void kernel_launch(void* const* d_in, const int* in_sizes, int n_in,
                              void* d_out, int out_size, void* d_ws, size_t ws_size,
                              hipStream_t stream) {
    const float* q_in = (const float*)d_in[0];
    const float* k_in = (const float*)d_in[1];
    const float* v_in = (const float*)d_in[2];
    const float* Wq   = (const float*)d_in[3];
    const float* bq   = (const float*)d_in[4];
    const float* Wk   = (const float*)d_in[5];
    const float* bk   = (const float*)d_in[6];
    const float* Wv   = (const float*)d_in[7];
    const float* bv   = (const float*)d_in[8];
    const float* Wo   = (const float*)d_in[9];
    const float* bo   = (const float*)d_in[10];

    char* ws = (char*)d_ws;
    const size_t MB = 1024ull * 1024ull;
    bf16_t* At  = (bf16_t*)(ws);             // attn out [4096][1024] bf16 (8 MB)
    bf16_t* Wtq = (bf16_t*)(ws + 24 * MB);
    bf16_t* Wtk = (bf16_t*)(ws + 26 * MB);
    bf16_t* Wtv = (bf16_t*)(ws + 28 * MB);
    bf16_t* Wto = (bf16_t*)(ws + 30 * MB);
    bf16_t* Qd  = (bf16_t*)(ws + 32 * MB);   // [bh][s][d]
    bf16_t* Kd  = (bf16_t*)(ws + 40 * MB);   // [bh][s][d]
    bf16_t* Vt  = (bf16_t*)(ws + 48 * MB);   // [bh][d][s]

    prep<<<1024, 256, 0, stream>>>(Wq, Wk, Wv, Wo, Wtq, Wtk, Wtv, Wto);

    gemm_qkv<<<dim3(32, 8, 3), 256, 0, stream>>>(q_in, k_in, v_in,
                                                 Wtq, Wtk, Wtv, bq, bk, bv, Qd, Kd, Vt);

    attn7<<<dim3(64, 8), 256, 0, stream>>>(Qd, Kd, Vt, At);

    gemm_out<<<dim3(64, 8), 256, 0, stream>>>(At, Wto, bo, (float*)d_out);
}

// Round 7
// 204.769 us; speedup vs baseline: 1.0324x; 1.0324x over previous
//
#include <hip/hip_runtime.h>
#include <hip/hip_bf16.h>
#include <cstdint>
#include <cstddef>

typedef __bf16 bf16_t;
typedef __bf16 bf16x8 __attribute__((ext_vector_type(8)));
typedef __bf16 bf16x4 __attribute__((ext_vector_type(4)));
typedef float f32x4 __attribute__((ext_vector_type(4)));

#define DM 1024
#define NHEAD 16
#define DHEAD 64

// Q scale folded into projection: 1/sqrt(64) * log2(e)
#define QSCALE 0.18033688011112042f
// fixed exp2 shift (cancels exactly in O/l)
#define PSHIFT 4.0f
// padded LDS row stride for attention tiles
#define RS 72

// counted vmcnt: lets N loads stay in flight across a raw barrier (T4)
#define WAITVM(N) asm volatile("s_waitcnt vmcnt(" #N ")" ::: "memory")
#define LGKM0()   asm volatile("s_waitcnt lgkmcnt(0)" ::: "memory")
#define BAR()     do { asm volatile("" ::: "memory"); __builtin_amdgcn_s_barrier(); \
                       asm volatile("" ::: "memory"); } while (0)

__device__ __forceinline__ void gload_lds16(const void* g, void* l) {
    __builtin_amdgcn_global_load_lds(
        (const __attribute__((address_space(1))) void*)g,
        (__attribute__((address_space(3))) void*)l,
        16, 0, 0);
}

__device__ __forceinline__ uint4 cvt8(float4 lo, float4 hi) {
    union { bf16_t b[8]; uint4 u; } o;
    o.b[0] = (bf16_t)lo.x; o.b[1] = (bf16_t)lo.y; o.b[2] = (bf16_t)lo.z; o.b[3] = (bf16_t)lo.w;
    o.b[4] = (bf16_t)hi.x; o.b[5] = (bf16_t)hi.y; o.b[6] = (bf16_t)hi.z; o.b[7] = (bf16_t)hi.w;
    return o.u;
}

// ---------------- prep: fused cast(3 tensors) + transpose(4 weights) --------
// (round-5 proven version; round-6's cast-fusion into gemm REVERTED)
__global__ void prep(
    const float* __restrict__ q_in, const float* __restrict__ k_in, const float* __restrict__ v_in,
    bf16_t* __restrict__ Xq, bf16_t* __restrict__ Xk, bf16_t* __restrict__ Xv,
    const float* __restrict__ w0, const float* __restrict__ w1,
    const float* __restrict__ w2, const float* __restrict__ w3,
    bf16_t* __restrict__ t0, bf16_t* __restrict__ t1,
    bf16_t* __restrict__ t2, bf16_t* __restrict__ t3)
{
    __shared__ float tile[64][65];
    int id = blockIdx.x;
    if (id < 6144) {
        int plane = id >> 11;
        int blk = id & 2047;
        const float* x = plane == 0 ? q_in : plane == 1 ? k_in : v_in;
        bf16_t* y      = plane == 0 ? Xq   : plane == 1 ? Xk   : Xv;
        int i = (blk * 256 + threadIdx.x) * 8;
        float4 lo = *(const float4*)&x[i];
        float4 hi = *(const float4*)&x[i + 4];
        *(uint4*)&y[i] = cvt8(lo, hi);
    } else {
        int t = id - 6144;
        int zi = t >> 8;
        int blk = t & 255;
        const float* w = zi == 0 ? w0 : zi == 1 ? w1 : zi == 2 ? w2 : w3;
        bf16_t* wt     = zi == 0 ? t0 : zi == 1 ? t1 : zi == 2 ? t2 : t3;
        int bx = (blk & 15) * 64;    // n base
        int by = (blk >> 4) * 64;    // k base
        int tx = threadIdx.x & 63, ty = threadIdx.x >> 6;   // 64 x 4
        for (int j = 0; j < 64; j += 4)
            tile[ty + j][tx] = w[(size_t)(by + ty + j) * DM + bx + tx];
        __syncthreads();
        int nl = threadIdx.x >> 3;           // 0..31
        int kl = (threadIdx.x & 7) * 8;      // 0..56
        for (int j = 0; j < 64; j += 32) {
            int n = nl + j;
            union { bf16_t b[8]; uint4 u; } o;
            for (int i = 0; i < 8; i++)
                o.b[i] = (bf16_t)tile[kl + i][n];
            *(uint4*)&wt[(size_t)(bx + n) * DM + by + kl] = o.u;
        }
    }
}

// ---- GEMM core: 128x128 tile, BK=32, 3-buffer depth-2 counted vmcnt --------
// (round-5 proven version, verbatim)
template <int MODE>
__device__ __forceinline__ void gemm_body(
    const bf16_t* __restrict__ A, const bf16_t* __restrict__ Bt,
    const float* __restrict__ bias, float scale,
    bf16_t* __restrict__ Cb,
    int r0, int c0, bf16_t* AsP, bf16_t* BsP)
{
    const int K = 1024;
    int tid  = threadIdx.x;
    int wave = tid >> 6;
    int lane = tid & 63;
    int quad = lane >> 4;
    int ln   = lane & 15;
    int wr   = wave >> 1;
    int wc   = wave & 1;

    f32x4 acc[4][4];
    for (int rb = 0; rb < 4; rb++)
        for (int cb = 0; cb < 4; cb++)
            acc[rb][cb] = (f32x4){0.f, 0.f, 0.f, 0.f};

    int sr = tid >> 2;
    // swizzled source chunk: c_src = c_dest ^ ((r>>1)&3)
    int sk = (((tid & 3) ^ ((tid >> 3) & 3))) * 8;

    const bf16_t* gA0 = &A[(size_t)(r0 + sr) * K + sk];
    const bf16_t* gA1 = gA0 + (size_t)64 * K;
    const bf16_t* gB0 = &Bt[(size_t)(c0 + sr) * K + sk];
    const bf16_t* gB1 = gB0 + (size_t)64 * K;
    char* lA = (char*)AsP + wave * 1024;   // slot stride 8192 B
    char* lB = (char*)BsP + wave * 1024;

    int ch = (quad ^ ((ln >> 1) & 3)) * 8;   // swizzled read chunk (elems)

    auto STAGE = [&](int s, int slot) {
        int k = s * 32;
        int off = slot * 8192;
        gload_lds16(gA0 + k, lA + off);
        gload_lds16(gA1 + k, lA + off + 4096);
        gload_lds16(gB0 + k, lB + off);
        gload_lds16(gB1 + k, lB + off + 4096);
    };
    auto COMPUTE = [&](int slot) {
        const bf16_t* Ab = AsP + slot * 4096;   // 4096 elems = 8 KB slot
        const bf16_t* Bb = BsP + slot * 4096;
        bf16x8 af[4], bfv[4];
        #pragma unroll
        for (int rb = 0; rb < 4; rb++)
            af[rb] = *(const bf16x8*)&Ab[(wr * 64 + rb * 16 + ln) * 32 + ch];
        #pragma unroll
        for (int cb = 0; cb < 4; cb++)
            bfv[cb] = *(const bf16x8*)&Bb[(wc * 64 + cb * 16 + ln) * 32 + ch];
        __builtin_amdgcn_s_setprio(1);
        #pragma unroll
        for (int rb = 0; rb < 4; rb++)
            #pragma unroll
            for (int cb = 0; cb < 4; cb++)
                acc[rb][cb] = __builtin_amdgcn_mfma_f32_16x16x32_bf16(af[rb], bfv[cb], acc[rb][cb], 0, 0, 0);
        __builtin_amdgcn_s_setprio(0);
    };

    STAGE(0, 0); STAGE(1, 1);
    WAITVM(4);           // retire t0's 4; t1's stay in flight
    BAR();

    for (int tt = 0; tt < 30; tt += 3) {
        STAGE(tt + 2, 2); COMPUTE(0); WAITVM(4); BAR();
        STAGE(tt + 3, 0); COMPUTE(1); WAITVM(4); BAR();
        STAGE(tt + 4, 1); COMPUTE(2); WAITVM(4); BAR();
    }
    COMPUTE(0); WAITVM(0); BAR();   // t=30; retire t31's loads
    COMPUTE(1);                      // t=31

    for (int rb = 0; rb < 4; rb++) {
        for (int cb = 0; cb < 4; cb++) {
            int C = c0 + wc * 64 + cb * 16 + ln;
            for (int r = 0; r < 4; r++) {
                int R = r0 + wr * 64 + rb * 16 + quad * 4 + r;
                float v = acc[rb][cb][r];
                if (MODE == 1) {
                    int b = R >> 10, s = R & 1023;
                    int h = C >> 6,  d = C & 63;
                    Cb[(((size_t)b * NHEAD + h) * 1024 + s) * DHEAD + d] =
                        (bf16_t)((v + bias[C]) * scale);
                } else {
                    Cb[((size_t)(C >> 10) * 1024 + R) * 1024 + (C & 1023)] =
                        (bf16_t)(v + bias[R]);
                }
            }
        }
    }
}

// grid (32, 8, 3): x = M-tile (XCD locality: id%8 = x%8), y = N-tile.
__global__ __launch_bounds__(256, 3) void gemm_qkv(
    const bf16_t* __restrict__ Xq, const bf16_t* __restrict__ Xk, const bf16_t* __restrict__ Xv,
    const bf16_t* __restrict__ Wtq, const bf16_t* __restrict__ Wtk, const bf16_t* __restrict__ Wtv,
    const float* __restrict__ bq, const float* __restrict__ bk, const float* __restrict__ bv,
    bf16_t* __restrict__ Qd, bf16_t* __restrict__ Kd, bf16_t* __restrict__ Vt)
{
    __shared__ __align__(16) bf16_t As[3 * 128 * 32];   // 24 KB
    __shared__ __align__(16) bf16_t Bs[3 * 128 * 32];   // 24 KB
    int z = blockIdx.z;
    if (z == 0) {
        gemm_body<1>(Xq, Wtq, bq, QSCALE, Qd,
                     blockIdx.x * 128, blockIdx.y * 128, As, Bs);
    } else if (z == 1) {
        gemm_body<1>(Xk, Wtk, bk, 1.0f, Kd,
                     blockIdx.x * 128, blockIdx.y * 128, As, Bs);
    } else {
        // Vt = (Xv Wv)^T : A = Wtv (8 channel tiles = y), B = Xv (32 token tiles = x)
        gemm_body<2>(Wtv, Xv, bv, 1.0f, Vt,
                     blockIdx.y * 128, blockIdx.x * 128, As, Bs);
    }
}

// ---------------- output projection: 64x128, 3-buffer depth-2 (round-5) -----
__global__ __launch_bounds__(256, 2) void gemm_out(
    const bf16_t* __restrict__ At, const bf16_t* __restrict__ Wto,
    const float* __restrict__ bo, float* __restrict__ out)
{
    const int K = 1024;
    __shared__ __align__(16) bf16_t As[3 * 64 * 32];    // 12 KB
    __shared__ __align__(16) bf16_t Bs[3 * 128 * 32];   // 24 KB

    int tid  = threadIdx.x;
    int wave = tid >> 6;
    int lane = tid & 63;
    int quad = lane >> 4;
    int ln   = lane & 15;

    int r0 = blockIdx.x * 64;
    int c0 = blockIdx.y * 128;

    f32x4 acc[4][2];
    for (int rb = 0; rb < 4; rb++)
        for (int cb = 0; cb < 2; cb++)
            acc[rb][cb] = (f32x4){0.f, 0.f, 0.f, 0.f};

    int sr = tid >> 2;
    int sk = (((tid & 3) ^ ((tid >> 3) & 3))) * 8;

    const bf16_t* gA0 = At  + (size_t)(r0 + sr) * K + sk;
    const bf16_t* gB0 = Wto + (size_t)(c0 + sr) * K + sk;
    const bf16_t* gB1 = gB0 + (size_t)64 * K;
    char* lA = (char*)As + wave * 1024;   // slot stride 4096 B
    char* lB = (char*)Bs + wave * 1024;   // slot stride 8192 B

    int ch = (quad ^ ((ln >> 1) & 3)) * 8;

    auto STAGE = [&](int s, int slot) {
        int k = s * 32;
        gload_lds16(gA0 + k, lA + slot * 4096);
        gload_lds16(gB0 + k, lB + slot * 8192);
        gload_lds16(gB1 + k, lB + slot * 8192 + 4096);
    };
    auto COMPUTE = [&](int slot) {
        const bf16_t* Ab = As + slot * 2048;
        const bf16_t* Bb = Bs + slot * 4096;
        bf16x8 af[4], bfv[2];
        #pragma unroll
        for (int rb = 0; rb < 4; rb++)
            af[rb] = *(const bf16x8*)&Ab[(rb * 16 + ln) * 32 + ch];
        #pragma unroll
        for (int cb = 0; cb < 2; cb++)
            bfv[cb] = *(const bf16x8*)&Bb[(wave * 32 + cb * 16 + ln) * 32 + ch];
        __builtin_amdgcn_s_setprio(1);
        #pragma unroll
        for (int rb = 0; rb < 4; rb++)
            #pragma unroll
            for (int cb = 0; cb < 2; cb++)
                acc[rb][cb] = __builtin_amdgcn_mfma_f32_16x16x32_bf16(af[rb], bfv[cb], acc[rb][cb], 0, 0, 0);
        __builtin_amdgcn_s_setprio(0);
    };

    STAGE(0, 0); STAGE(1, 1);
    WAITVM(3);
    BAR();

    for (int tt = 0; tt < 30; tt += 3) {
        STAGE(tt + 2, 2); COMPUTE(0); WAITVM(3); BAR();
        STAGE(tt + 3, 0); COMPUTE(1); WAITVM(3); BAR();
        STAGE(tt + 4, 1); COMPUTE(2); WAITVM(3); BAR();
    }
    COMPUTE(0); WAITVM(0); BAR();
    COMPUTE(1);

    for (int rb = 0; rb < 4; rb++) {
        for (int cb = 0; cb < 2; cb++) {
            int C = c0 + wave * 32 + cb * 16 + ln;
            float bn = bo[C];
            for (int r = 0; r < 4; r++) {
                int R = r0 + rb * 16 + quad * 4 + r;
                out[(size_t)R * DM + C] = acc[rb][cb][r] + bn;
            }
        }
    }
}

// ---------------- flash attention: 64 q-rows per wave (h=4) -----------------
// K/V LDS dbuf + 1 raw barrier/kt (round-5 sync structure). Doubling q/wave
// again amortizes the per-wave full-tile K/V LDS re-reads over 2x output:
// LDS bytes per q-row ~0.69x of h=2. grid (64, 4): 256 blocks = 1/CU.
// QK^T restructured per-kb so sc stays 4 transient regs (bounds VGPR).
__global__ __launch_bounds__(256) void attn8(
    const bf16_t* __restrict__ Q,
    const bf16_t* __restrict__ K,
    const bf16_t* __restrict__ Vt,
    bf16_t* __restrict__ O)
{
    __shared__ __align__(16) bf16_t Ks[2][64 * RS];   // 18 KB
    __shared__ __align__(16) bf16_t Vs[2][64 * RS];   // 18 KB
    __shared__ __align__(16) bf16_t Ps[4][64 * RS];   // 36 KB

    int tid  = threadIdx.x;
    int wave = tid >> 6;
    int lane = tid & 63;
    int quad = lane >> 4;
    int ln   = lane & 15;

    int bh = blockIdx.x;
    int q0w = blockIdx.y * 256 + wave * 64;

    const bf16_t* Qb = Q  + (size_t)bh * 65536;
    const bf16_t* Kb = K  + (size_t)bh * 65536;
    const bf16_t* Vb = Vt + (size_t)bh * 65536;

    int srow = tid >> 3;
    int scol = (tid & 7) * 8;
    const bf16_t* gK0 = Kb + (size_t)srow * 64 + scol;
    const bf16_t* gK1 = gK0 + 32 * 64;
    const bf16_t* gV0 = Vb + (size_t)srow * 1024 + scol;
    const bf16_t* gV1 = gV0 + 32 * 1024;

    bf16x8 aq0[4], aq1[4];
    #pragma unroll
    for (int h = 0; h < 4; h++) {
        aq0[h] = *(const bf16x8*)&Qb[(size_t)(q0w + h * 16 + ln) * 64 + quad * 8];
        aq1[h] = *(const bf16x8*)&Qb[(size_t)(q0w + h * 16 + ln) * 64 + 32 + quad * 8];
    }

    // prologue: kt=0 -> buf0; prefetch kt=1 into regs
    uint4 rK0 = *(const uint4*)gK0;
    uint4 rK1 = *(const uint4*)gK1;
    uint4 rV0 = *(const uint4*)gV0;
    uint4 rV1 = *(const uint4*)gV1;
    *(uint4*)&Ks[0][srow * RS + scol]        = rK0;
    *(uint4*)&Ks[0][(32 + srow) * RS + scol] = rK1;
    *(uint4*)&Vs[0][srow * RS + scol]        = rV0;
    *(uint4*)&Vs[0][(32 + srow) * RS + scol] = rV1;
    gK0 += 4096; gK1 += 4096; gV0 += 64; gV1 += 64;
    rK0 = *(const uint4*)gK0;
    rK1 = *(const uint4*)gK1;
    rV0 = *(const uint4*)gV0;
    rV1 = *(const uint4*)gV1;

    float l_lane[4] = {0.f, 0.f, 0.f, 0.f};
    f32x4 o_acc[4][4];
    #pragma unroll
    for (int h = 0; h < 4; h++)
        #pragma unroll
        for (int cb = 0; cb < 4; cb++)
            o_acc[h][cb] = (f32x4){0.f, 0.f, 0.f, 0.f};

    bf16_t* Pw = Ps[wave];

    LGKM0();
    BAR();

    for (int kt = 0; kt < 16; kt++) {
        const bf16_t* Kc = Ks[kt & 1];
        const bf16_t* Vc = Vs[kt & 1];
        bf16_t* Kn = Ks[(kt + 1) & 1];
        bf16_t* Vn = Vs[(kt + 1) & 1];

        if (kt < 15) {
            // store kt+1 regs into the buffer whose readers (kt-1) are done
            *(uint4*)&Kn[srow * RS + scol]        = rK0;
            *(uint4*)&Kn[(32 + srow) * RS + scol] = rK1;
            *(uint4*)&Vn[srow * RS + scol]        = rV0;
            *(uint4*)&Vn[(32 + srow) * RS + scol] = rV1;
        }
        if (kt < 14) {
            gK0 += 4096; gK1 += 4096; gV0 += 64; gV1 += 64;
            rK0 = *(const uint4*)gK0;
            rK1 = *(const uint4*)gK1;
            rV0 = *(const uint4*)gV0;
            rV1 = *(const uint4*)gV1;
        }

        // ---- S^T = K Q^T, P = exp2(S - PSHIFT), per kb (sc transient) ----
        #pragma unroll
        for (int kb = 0; kb < 4; kb++) {
            bf16x8 kf0 = *(const bf16x8*)&Kc[(kb * 16 + ln) * RS + quad * 8];
            bf16x8 kf1 = *(const bf16x8*)&Kc[(kb * 16 + ln) * RS + 32 + quad * 8];
            #pragma unroll
            for (int h = 0; h < 4; h++) {
                f32x4 a = (f32x4){0.f, 0.f, 0.f, 0.f};
                a = __builtin_amdgcn_mfma_f32_16x16x32_bf16(kf0, aq0[h], a, 0, 0, 0);
                a = __builtin_amdgcn_mfma_f32_16x16x32_bf16(kf1, aq1[h], a, 0, 0, 0);
                float p0 = __builtin_amdgcn_exp2f(a[0] - PSHIFT);
                float p1 = __builtin_amdgcn_exp2f(a[1] - PSHIFT);
                float p2 = __builtin_amdgcn_exp2f(a[2] - PSHIFT);
                float p3 = __builtin_amdgcn_exp2f(a[3] - PSHIFT);
                l_lane[h] += (p0 + p1) + (p2 + p3);
                bf16x4 pk = (bf16x4){(bf16_t)p0, (bf16_t)p1, (bf16_t)p2, (bf16_t)p3};
                *(bf16x4*)&Pw[(h * 16 + ln) * RS + kb * 16 + quad * 4] = pk;
            }
        }

        // ---- O += P V (V fragments shared across all 4 q-halves) ----
        #pragma unroll
        for (int kc = 0; kc < 2; kc++) {
            bf16x8 ap[4];
            #pragma unroll
            for (int h = 0; h < 4; h++)
                ap[h] = *(const bf16x8*)&Pw[(h * 16 + ln) * RS + kc * 32 + quad * 8];
            #pragma unroll
            for (int cb = 0; cb < 4; cb++) {
                bf16x8 vf = *(const bf16x8*)&Vc[(cb * 16 + ln) * RS + kc * 32 + quad * 8];
                #pragma unroll
                for (int h = 0; h < 4; h++)
                    o_acc[h][cb] = __builtin_amdgcn_mfma_f32_16x16x32_bf16(ap[h], vf, o_acc[h][cb], 0, 0, 0);
            }
        }

        if (kt < 15) {
            LGKM0();   // publish kt+1 stores (reads drained by MFMA deps)
            BAR();     // vmcnt prefetch stays in flight
        }
    }

    int b = bh >> 4, hd = bh & 15;
    for (int h = 0; h < 4; h++) {
        float l = l_lane[h];
        l += __shfl_xor(l, 16);
        l += __shfl_xor(l, 32);
        float invq[4];
        for (int r = 0; r < 4; r++)
            invq[r] = 1.f / __shfl(l, quad * 4 + r);
        for (int cb = 0; cb < 4; cb++) {
            for (int r = 0; r < 4; r++) {
                int q = q0w + h * 16 + quad * 4 + r;
                int d = cb * 16 + ln;
                O[((size_t)b * 1024 + q) * DM + hd * 64 + d] = (bf16_t)(o_acc[h][cb][r] * invq[r]);
            }
        }
    }
}

extern "C" void kernel_launch(void* const* d_in, const int* in_sizes, int n_in,
                              void* d_out, int out_size, void* d_ws, size_t ws_size,
                              hipStream_t stream) {
    const float* q_in = (const float*)d_in[0];
    const float* k_in = (const float*)d_in[1];
    const float* v_in = (const float*)d_in[2];
    const float* Wq   = (const float*)d_in[3];
    const float* bq   = (const float*)d_in[4];
    const float* Wk   = (const float*)d_in[5];
    const float* bk   = (const float*)d_in[6];
    const float* Wv   = (const float*)d_in[7];
    const float* bv   = (const float*)d_in[8];
    const float* Wo   = (const float*)d_in[9];
    const float* bo   = (const float*)d_in[10];

    char* ws = (char*)d_ws;
    const size_t MB = 1024ull * 1024ull;
    bf16_t* Xq  = (bf16_t*)(ws);             // 8 MB
    bf16_t* Xk  = (bf16_t*)(ws + 8 * MB);
    bf16_t* Xv  = (bf16_t*)(ws + 16 * MB);
    bf16_t* Wtq = (bf16_t*)(ws + 24 * MB);
    bf16_t* Wtk = (bf16_t*)(ws + 26 * MB);
    bf16_t* Wtv = (bf16_t*)(ws + 28 * MB);
    bf16_t* Wto = (bf16_t*)(ws + 30 * MB);
    bf16_t* Qd  = (bf16_t*)(ws + 32 * MB);   // [bh][s][d]
    bf16_t* Kd  = (bf16_t*)(ws + 40 * MB);   // [bh][s][d]
    bf16_t* Vt  = (bf16_t*)(ws + 48 * MB);   // [bh][d][s]
    bf16_t* At  = Xq;                        // attn out aliases Xq (dead by then)

    prep<<<7168, 256, 0, stream>>>(q_in, k_in, v_in, Xq, Xk, Xv,
                                   Wq, Wk, Wv, Wo, Wtq, Wtk, Wtv, Wto);

    gemm_qkv<<<dim3(32, 8, 3), 256, 0, stream>>>(Xq, Xk, Xv,
                                                 Wtq, Wtk, Wtv, bq, bk, bv, Qd, Kd, Vt);

    attn8<<<dim3(64, 4), 256, 0, stream>>>(Qd, Kd, Vt, At);

    gemm_out<<<dim3(64, 8), 256, 0, stream>>>(At, Wto, bo, (float*)d_out);
}